// Round 8
// baseline (317.991 us; speedup 1.0000x reference)
//
#include <hip/hip_runtime.h>
#include <cmath>

// Problem constants
#define T_LEN   160000
#define C_ROWS  256
#define SEG     125                 // samples per segment
#define NSEG    1280                // T_LEN / SEG
#define SCAN_BLOCKS 10
#define SEGS_PER_BLOCK 128          // NSEG / SCAN_BLOCKS
#define CHUNK   5                   // segments per thread in phase 2 (NSEG/256)
#define K2_THREADS 256
#define PI_D    3.14159265358979323846

// mul_kernel geometry: 2500 blocks x 256 threads = 640,000 threads = exactly
// 16 rows of f4 columns (ROW_F4 = 40,000). Grid stride = 16 rows; each
// thread keeps ONE time-column -> mod f4 in a register.
// Flag matrix (measured across rounds, totals):
//   NT load + NT store      : 297-301  (R0/R4)  -- full 328 MB HBM traffic
//   plain   + plain         : 314.6    (R7)     -- plain stores evict x from L3
//   plain   + NT (serial)   : 310-317  (R1-R3)  -- body was latency-serialized
//   plain   + NT (stride)   : THIS ROUND        -- 253 MB traffic (L3 serves
//                             ~50% of x: FETCH 87MB measured R1/R2) at the
//                             grid-stride pump rate.
#define ROW_F4        40000
#define MUL_THREADS   256
#define MUL_BLOCKS    2500
#define MUL_STRIDE_F4 (MUL_BLOCKS * MUL_THREADS)   // 640,000 f4 = 16 rows
#define MUL_ITERS     16                           // 256 rows / 16

typedef float fvec4 __attribute__((ext_vector_type(4)));

struct IIRParams {
    float b0, b1, b2, a1, a2;       // f32-rounded biquad coefficients
    double h00, h01, h10, h11;      // H = A^SEG (f64), A = [[-a1,-a2],[1,0]]
};

// ---------------------------------------------------------------------------
// Phase 1: zero-init scan per segment -> segment offset (f1,f2).
// ---------------------------------------------------------------------------
__global__ __launch_bounds__(SEGS_PER_BLOCK)
void iir_phase1(const float* __restrict__ noise,
                float* __restrict__ F1, float* __restrict__ F2,
                IIRParams p) {
    __shared__ float sx[SEGS_PER_BLOCK * SEG];      // 16000 f32 = 62.5 KB
    const int tid = threadIdx.x;
    const int blk = blockIdx.x;
    const int blkBase = blk * SEGS_PER_BLOCK * SEG; // float offset

    const fvec4* n4 = (const fvec4*)(noise + blkBase);
    fvec4* s4 = (fvec4*)sx;
    for (int i = tid; i < (SEGS_PER_BLOCK * SEG) / 4; i += SEGS_PER_BLOCK) {
        fvec4 v = n4[i];
        s4[i] = v * 0.5f;                            // FACTOR (exact)
    }
    __syncthreads();

    const int g = blk * SEGS_PER_BLOCK + tid;       // global segment id
    const int lofs = tid * SEG;
    float px1 = 0.f, px2 = 0.f;                     // x-history entering segment
    if (tid > 0)      { px1 = sx[lofs - 1]; px2 = sx[lofs - 2]; }
    else if (blk > 0) { px1 = 0.5f * noise[blkBase - 1];
                        px2 = 0.5f * noise[blkBase - 2]; }

    float x1 = px1, x2 = px2, y1 = 0.f, y2 = 0.f;
    #pragma unroll 5
    for (int j = 0; j < SEG; ++j) {
        float xn = sx[lofs + j];
        float w  = fmaf(p.b0, xn, fmaf(p.b1, x1, p.b2 * x2));
        float y  = fmaf(-p.a1, y1, fmaf(-p.a2, y2, w));
        x2 = x1; x1 = xn; y2 = y1; y1 = y;
    }
    F1[g] = y1;
    F2[g] = y2;
}

// ---------------------------------------------------------------------------
// Phase 2: compose 1280 affine maps (H, f_g) -> init state per segment.
// ---------------------------------------------------------------------------
__global__ __launch_bounds__(K2_THREADS)
void iir_phase2(const float* __restrict__ F1, const float* __restrict__ F2,
                float* __restrict__ I1, float* __restrict__ I2,
                IIRParams p) {
    __shared__ double sA00[K2_THREADS], sA01[K2_THREADS],
                      sA10[K2_THREADS], sA11[K2_THREADS],
                      sB0[K2_THREADS],  sB1[K2_THREADS];
    const int t = threadIdx.x;
    const double h00 = p.h00, h01 = p.h01, h10 = p.h10, h11 = p.h11;

    double f0[CHUNK], f1v[CHUNK];
    for (int k = 0; k < CHUNK; ++k) {
        f0[k]  = (double)F1[t * CHUNK + k];
        f1v[k] = (double)F2[t * CHUNK + k];
    }
    // chunk map: state -> H^5 * state + b   (segment 5t applied first)
    double A00 = 1, A01 = 0, A10 = 0, A11 = 1, b0v = 0, b1v = 0;
    for (int k = 0; k < CHUNK; ++k) {
        double nb0 = h00 * b0v + h01 * b1v + f0[k];
        double nb1 = h10 * b0v + h11 * b1v + f1v[k];
        b0v = nb0; b1v = nb1;
        double t00 = h00*A00 + h01*A10, t01 = h00*A01 + h01*A11;
        double t10 = h10*A00 + h11*A10, t11 = h10*A01 + h11*A11;
        A00 = t00; A01 = t01; A10 = t10; A11 = t11;
    }
    sA00[t]=A00; sA01[t]=A01; sA10[t]=A10; sA11[t]=A11; sB0[t]=b0v; sB1[t]=b1v;
    __syncthreads();

    // inclusive scan; element t = chunk_0 ∘ ... ∘ chunk_t (chunk_0 first)
    for (int off = 1; off < K2_THREADS; off <<= 1) {
        double pA00=0,pA01=0,pA10=0,pA11=0,pB0=0,pB1=0;
        const bool act = (t >= off);
        if (act) { pA00=sA00[t-off]; pA01=sA01[t-off]; pA10=sA10[t-off];
                   pA11=sA11[t-off]; pB0 =sB0[t-off];  pB1 =sB1[t-off]; }
        double c00=sA00[t], c01=sA01[t], c10=sA10[t], c11=sA11[t],
               cb0=sB0[t],  cb1=sB1[t];
        __syncthreads();
        if (act) {
            // cur ∘ prev : A = c*p, b = c*pb + cb
            sA00[t] = c00*pA00 + c01*pA10;
            sA01[t] = c00*pA01 + c01*pA11;
            sA10[t] = c10*pA00 + c11*pA10;
            sA11[t] = c10*pA01 + c11*pA11;
            sB0[t]  = c00*pB0  + c01*pB1 + cb0;
            sB1[t]  = c10*pB0  + c11*pB1 + cb1;
        }
        __syncthreads();
    }

    // state entering this thread's chunk = exclusive-scan offset (init = 0)
    double s0 = 0.0, s1 = 0.0;
    if (t > 0) { s0 = sB0[t-1]; s1 = sB1[t-1]; }
    for (int k = 0; k < CHUNK; ++k) {
        I1[t * CHUNK + k] = (float)s0;
        I2[t * CHUNK + k] = (float)s1;
        double n0 = h00 * s0 + h01 * s1 + f0[k];
        double n1 = h10 * s0 + h11 * s1 + f1v[k];
        s0 = n0; s1 = n1;
    }
}

// ---------------------------------------------------------------------------
// Phase 3: true-init scan, write mod = y + 1 (in-place in LDS, coalesced out)
// ---------------------------------------------------------------------------
__global__ __launch_bounds__(SEGS_PER_BLOCK)
void iir_phase3(const float* __restrict__ noise,
                const float* __restrict__ I1, const float* __restrict__ I2,
                float* __restrict__ mod, IIRParams p) {
    __shared__ float sx[SEGS_PER_BLOCK * SEG];
    const int tid = threadIdx.x;
    const int blk = blockIdx.x;
    const int blkBase = blk * SEGS_PER_BLOCK * SEG;

    const fvec4* n4 = (const fvec4*)(noise + blkBase);
    fvec4* s4 = (fvec4*)sx;
    for (int i = tid; i < (SEGS_PER_BLOCK * SEG) / 4; i += SEGS_PER_BLOCK) {
        fvec4 v = n4[i];
        s4[i] = v * 0.5f;
    }
    __syncthreads();

    const int g = blk * SEGS_PER_BLOCK + tid;
    const int lofs = tid * SEG;
    float px1 = 0.f, px2 = 0.f;
    if (tid > 0)      { px1 = sx[lofs - 1]; px2 = sx[lofs - 2]; }
    else if (blk > 0) { px1 = 0.5f * noise[blkBase - 1];
                        px2 = 0.5f * noise[blkBase - 2]; }
    __syncthreads();   // all history reads done before in-place overwrite

    float x1 = px1, x2 = px2, y1 = I1[g], y2 = I2[g];
    for (int j = 0; j < SEG; ++j) {
        float xn = sx[lofs + j];
        float w  = fmaf(p.b0, xn, fmaf(p.b1, x1, p.b2 * x2));
        float y  = fmaf(-p.a1, y1, fmaf(-p.a2, y2, w));
        sx[lofs + j] = y + 1.0f;                    // mod value, in place
        x2 = x1; x1 = xn; y2 = y1; y1 = y;
    }
    __syncthreads();

    fvec4* m4 = (fvec4*)(mod + blkBase);
    for (int i = tid; i < (SEGS_PER_BLOCK * SEG) / 4; i += SEGS_PER_BLOCK) {
        m4[i] = s4[i];
    }
}

// ---------------------------------------------------------------------------
// out[c,t] = x[c,t] * mod[t] — grid-stride multiply, plain load + NT store.
// Thread tid owns f4 column (tid % ROW_F4) in rows {tid/ROW_F4 + 16k}.
// Plain x load: L3-cacheable (FETCH 87MB vs 164MB measured R1/R2 = ~50% hit).
// NT out store: does NOT allocate in L2/L3, so the 164MB write stream cannot
// evict x from the Infinity Cache (R7 showed plain stores do exactly that:
// plain/plain was 14us slower than NT/NT). Full unroll keeps the compiler's
// counted-vmcnt pipeline: register reuse is 16 iterations apart.
// ---------------------------------------------------------------------------
__global__ __launch_bounds__(MUL_THREADS)
void mul_kernel(const float* __restrict__ x, const float* __restrict__ mod,
                float* __restrict__ out) {
    const int tid = blockIdx.x * MUL_THREADS + threadIdx.x;  // 0..639,999
    const int t4 = tid % ROW_F4;                             // time column
    const fvec4 mv = *(const fvec4*)(mod + 4 * t4);
    const fvec4* __restrict__ x4 = (const fvec4*)x;
    fvec4* __restrict__ o4 = (fvec4*)out;

    int idx = tid;
    #pragma unroll
    for (int it = 0; it < MUL_ITERS; ++it) {
        fvec4 xv = x4[idx];                       // plain: L3 serves ~50%
        __builtin_nontemporal_store(xv * mv, &o4[idx]);  // no L3 allocation
        idx += MUL_STRIDE_F4;
    }
}

extern "C" void kernel_launch(void* const* d_in, const int* in_sizes, int n_in,
                              void* d_out, int out_size, void* d_ws, size_t ws_size,
                              hipStream_t stream) {
    const float* x     = (const float*)d_in[0];   // (256, 160000) f32
    const float* noise = (const float*)d_in[1];   // (1, 160000)  f32
    float* out = (float*)d_out;
    float* mod = (float*)d_ws;                    // 160000 f32
    float* F1  = mod + T_LEN;                     // NSEG f32 each
    float* F2  = F1 + NSEG;
    float* I1  = F2 + NSEG;
    float* I2  = I1 + NSEG;

    // Host-side coefficient + H = A^SEG computation (baked into graph args)
    IIRParams p;
    {
        const double w0    = 2.0 * PI_D * 1.0 / 16000.0;  // cutoff = 1 Hz
        const double alpha = sin(w0) / (2.0 * 0.707);
        const double cosw  = cos(w0);
        const double a0    = 1.0 + alpha;
        p.b0 = (float)((1.0 - cosw) / 2.0 / a0);
        p.b1 = (float)((1.0 - cosw) / a0);
        p.b2 = p.b0;
        p.a1 = (float)(-2.0 * cosw / a0);
        p.a2 = (float)((1.0 - alpha) / a0);

        double m00 = -(double)p.a1, m01 = -(double)p.a2, m10 = 1.0, m11 = 0.0;
        double h00 = 1, h01 = 0, h10 = 0, h11 = 1;
        int e = SEG;
        while (e > 0) {
            if (e & 1) {
                double t00 = h00*m00 + h01*m10, t01 = h00*m01 + h01*m11;
                double t10 = h10*m00 + h11*m10, t11 = h10*m01 + h11*m11;
                h00 = t00; h01 = t01; h10 = t10; h11 = t11;
            }
            e >>= 1;
            if (e) {
                double t00 = m00*m00 + m01*m10, t01 = m00*m01 + m01*m11;
                double t10 = m10*m00 + m11*m10, t11 = m10*m01 + m11*m11;
                m00 = t00; m01 = t01; m10 = t10; m11 = t11;
            }
        }
        p.h00 = h00; p.h01 = h01; p.h10 = h10; p.h11 = h11;
    }

    iir_phase1<<<SCAN_BLOCKS, SEGS_PER_BLOCK, 0, stream>>>(noise, F1, F2, p);
    iir_phase2<<<1, K2_THREADS, 0, stream>>>(F1, F2, I1, I2, p);
    iir_phase3<<<SCAN_BLOCKS, SEGS_PER_BLOCK, 0, stream>>>(noise, I1, I2, mod, p);

    mul_kernel<<<MUL_BLOCKS, MUL_THREADS, 0, stream>>>(x, mod, out);
}

// Round 9
// 298.911 us; speedup vs baseline: 1.0638x; 1.0638x over previous
//
#include <hip/hip_runtime.h>
#include <cmath>

// Problem constants
#define T_LEN   160000
#define C_ROWS  256
#define SEG     125                 // samples per segment
#define NSEG    1280                // T_LEN / SEG
#define SCAN_BLOCKS 10
#define SEGS_PER_BLOCK 128          // NSEG / SCAN_BLOCKS
#define CHUNK   5                   // segments per thread in phase 2 (NSEG/256)
#define K2_THREADS 256
#define PI_D    3.14159265358979323846

// mul_kernel: settled evidence after the full {NT,plain}x{NT,plain} matrix
// (R0-R8): NT load + NT store is the fastest arm (R0/R4 ~3.8 TB/s; every
// plain-load arm = 3.3 TB/s wall time despite 24% less HBM traffic -- the
// L3-hit read path pumps SLOWER than the NT HBM path). Per-thread loops are
// poison: the allocator caps VGPR at 16-32 and serializes to ~2 ops in
// flight (5 failed attempts incl. sched_barrier and asm). So: R0's
// serialization-proof 1-load/1-store body, but 1024-thread blocks ->
// 10,000 blocks instead of 40,000. R0's 85us sat exactly at the ~470
// blocks/us turnover rate; this 4x cut separates launch-rate-limited
// (-> ~55-65us) from memory-wall (-> unchanged ~86us => ROOFLINE).
#define ROW_F4        40000
#define MUL_THREADS   1024
#define MUL_BLOCKS    ((C_ROWS * T_LEN / 4) / MUL_THREADS)   // 10,000

typedef float fvec4 __attribute__((ext_vector_type(4)));

struct IIRParams {
    float b0, b1, b2, a1, a2;       // f32-rounded biquad coefficients
    double h00, h01, h10, h11;      // H = A^SEG (f64), A = [[-a1,-a2],[1,0]]
};

// ---------------------------------------------------------------------------
// Phase 1: zero-init scan per segment -> segment offset (f1,f2).
// ---------------------------------------------------------------------------
__global__ __launch_bounds__(SEGS_PER_BLOCK)
void iir_phase1(const float* __restrict__ noise,
                float* __restrict__ F1, float* __restrict__ F2,
                IIRParams p) {
    __shared__ float sx[SEGS_PER_BLOCK * SEG];      // 16000 f32 = 62.5 KB
    const int tid = threadIdx.x;
    const int blk = blockIdx.x;
    const int blkBase = blk * SEGS_PER_BLOCK * SEG; // float offset

    const fvec4* n4 = (const fvec4*)(noise + blkBase);
    fvec4* s4 = (fvec4*)sx;
    for (int i = tid; i < (SEGS_PER_BLOCK * SEG) / 4; i += SEGS_PER_BLOCK) {
        fvec4 v = n4[i];
        s4[i] = v * 0.5f;                            // FACTOR (exact)
    }
    __syncthreads();

    const int g = blk * SEGS_PER_BLOCK + tid;       // global segment id
    const int lofs = tid * SEG;
    float px1 = 0.f, px2 = 0.f;                     // x-history entering segment
    if (tid > 0)      { px1 = sx[lofs - 1]; px2 = sx[lofs - 2]; }
    else if (blk > 0) { px1 = 0.5f * noise[blkBase - 1];
                        px2 = 0.5f * noise[blkBase - 2]; }

    float x1 = px1, x2 = px2, y1 = 0.f, y2 = 0.f;
    #pragma unroll 5
    for (int j = 0; j < SEG; ++j) {
        float xn = sx[lofs + j];
        float w  = fmaf(p.b0, xn, fmaf(p.b1, x1, p.b2 * x2));
        float y  = fmaf(-p.a1, y1, fmaf(-p.a2, y2, w));
        x2 = x1; x1 = xn; y2 = y1; y1 = y;
    }
    F1[g] = y1;
    F2[g] = y2;
}

// ---------------------------------------------------------------------------
// Phase 2: compose 1280 affine maps (H, f_g) -> init state per segment.
// ---------------------------------------------------------------------------
__global__ __launch_bounds__(K2_THREADS)
void iir_phase2(const float* __restrict__ F1, const float* __restrict__ F2,
                float* __restrict__ I1, float* __restrict__ I2,
                IIRParams p) {
    __shared__ double sA00[K2_THREADS], sA01[K2_THREADS],
                      sA10[K2_THREADS], sA11[K2_THREADS],
                      sB0[K2_THREADS],  sB1[K2_THREADS];
    const int t = threadIdx.x;
    const double h00 = p.h00, h01 = p.h01, h10 = p.h10, h11 = p.h11;

    double f0[CHUNK], f1v[CHUNK];
    for (int k = 0; k < CHUNK; ++k) {
        f0[k]  = (double)F1[t * CHUNK + k];
        f1v[k] = (double)F2[t * CHUNK + k];
    }
    // chunk map: state -> H^5 * state + b   (segment 5t applied first)
    double A00 = 1, A01 = 0, A10 = 0, A11 = 1, b0v = 0, b1v = 0;
    for (int k = 0; k < CHUNK; ++k) {
        double nb0 = h00 * b0v + h01 * b1v + f0[k];
        double nb1 = h10 * b0v + h11 * b1v + f1v[k];
        b0v = nb0; b1v = nb1;
        double t00 = h00*A00 + h01*A10, t01 = h00*A01 + h01*A11;
        double t10 = h10*A00 + h11*A10, t11 = h10*A01 + h11*A11;
        A00 = t00; A01 = t01; A10 = t10; A11 = t11;
    }
    sA00[t]=A00; sA01[t]=A01; sA10[t]=A10; sA11[t]=A11; sB0[t]=b0v; sB1[t]=b1v;
    __syncthreads();

    // inclusive scan; element t = chunk_0 ∘ ... ∘ chunk_t (chunk_0 first)
    for (int off = 1; off < K2_THREADS; off <<= 1) {
        double pA00=0,pA01=0,pA10=0,pA11=0,pB0=0,pB1=0;
        const bool act = (t >= off);
        if (act) { pA00=sA00[t-off]; pA01=sA01[t-off]; pA10=sA10[t-off];
                   pA11=sA11[t-off]; pB0 =sB0[t-off];  pB1 =sB1[t-off]; }
        double c00=sA00[t], c01=sA01[t], c10=sA10[t], c11=sA11[t],
               cb0=sB0[t],  cb1=sB1[t];
        __syncthreads();
        if (act) {
            // cur ∘ prev : A = c*p, b = c*pb + cb
            sA00[t] = c00*pA00 + c01*pA10;
            sA01[t] = c00*pA01 + c01*pA11;
            sA10[t] = c10*pA00 + c11*pA10;
            sA11[t] = c10*pA01 + c11*pA11;
            sB0[t]  = c00*pB0  + c01*pB1 + cb0;
            sB1[t]  = c10*pB0  + c11*pB1 + cb1;
        }
        __syncthreads();
    }

    // state entering this thread's chunk = exclusive-scan offset (init = 0)
    double s0 = 0.0, s1 = 0.0;
    if (t > 0) { s0 = sB0[t-1]; s1 = sB1[t-1]; }
    for (int k = 0; k < CHUNK; ++k) {
        I1[t * CHUNK + k] = (float)s0;
        I2[t * CHUNK + k] = (float)s1;
        double n0 = h00 * s0 + h01 * s1 + f0[k];
        double n1 = h10 * s0 + h11 * s1 + f1v[k];
        s0 = n0; s1 = n1;
    }
}

// ---------------------------------------------------------------------------
// Phase 3: true-init scan, write mod = y + 1 (in-place in LDS, coalesced out)
// ---------------------------------------------------------------------------
__global__ __launch_bounds__(SEGS_PER_BLOCK)
void iir_phase3(const float* __restrict__ noise,
                const float* __restrict__ I1, const float* __restrict__ I2,
                float* __restrict__ mod, IIRParams p) {
    __shared__ float sx[SEGS_PER_BLOCK * SEG];
    const int tid = threadIdx.x;
    const int blk = blockIdx.x;
    const int blkBase = blk * SEGS_PER_BLOCK * SEG;

    const fvec4* n4 = (const fvec4*)(noise + blkBase);
    fvec4* s4 = (fvec4*)sx;
    for (int i = tid; i < (SEGS_PER_BLOCK * SEG) / 4; i += SEGS_PER_BLOCK) {
        fvec4 v = n4[i];
        s4[i] = v * 0.5f;
    }
    __syncthreads();

    const int g = blk * SEGS_PER_BLOCK + tid;
    const int lofs = tid * SEG;
    float px1 = 0.f, px2 = 0.f;
    if (tid > 0)      { px1 = sx[lofs - 1]; px2 = sx[lofs - 2]; }
    else if (blk > 0) { px1 = 0.5f * noise[blkBase - 1];
                        px2 = 0.5f * noise[blkBase - 2]; }
    __syncthreads();   // all history reads done before in-place overwrite

    float x1 = px1, x2 = px2, y1 = I1[g], y2 = I2[g];
    for (int j = 0; j < SEG; ++j) {
        float xn = sx[lofs + j];
        float w  = fmaf(p.b0, xn, fmaf(p.b1, x1, p.b2 * x2));
        float y  = fmaf(-p.a1, y1, fmaf(-p.a2, y2, w));
        sx[lofs + j] = y + 1.0f;                    // mod value, in place
        x2 = x1; x1 = xn; y2 = y1; y1 = y;
    }
    __syncthreads();

    fvec4* m4 = (fvec4*)(mod + blkBase);
    for (int i = tid; i < (SEGS_PER_BLOCK * SEG) / 4; i += SEGS_PER_BLOCK) {
        m4[i] = s4[i];
    }
}

// ---------------------------------------------------------------------------
// out[c,t] = x[c,t] * mod[t] — one f4 per thread, NT load + NT store
// (fastest flag arm, R0/R4). 1024-thread blocks -> 10,000 blocks: 4x fewer
// launches than R0 at identical per-thread code, isolating launch-rate vs
// memory-wall. No per-thread loop => nothing for the allocator to serialize.
// ---------------------------------------------------------------------------
__global__ __launch_bounds__(MUL_THREADS)
void mul_kernel(const fvec4* __restrict__ x4, const float* __restrict__ mod,
                fvec4* __restrict__ out4) {
    const int f = blockIdx.x * MUL_THREADS + threadIdx.x;    // f4 index
    const int t4 = f % ROW_F4;                               // time column
    fvec4 xv = __builtin_nontemporal_load(&x4[f]);
    fvec4 mv = *(const fvec4*)(mod + 4 * t4);
    __builtin_nontemporal_store(xv * mv, &out4[f]);
}

extern "C" void kernel_launch(void* const* d_in, const int* in_sizes, int n_in,
                              void* d_out, int out_size, void* d_ws, size_t ws_size,
                              hipStream_t stream) {
    const float* x     = (const float*)d_in[0];   // (256, 160000) f32
    const float* noise = (const float*)d_in[1];   // (1, 160000)  f32
    float* out = (float*)d_out;
    float* mod = (float*)d_ws;                    // 160000 f32
    float* F1  = mod + T_LEN;                     // NSEG f32 each
    float* F2  = F1 + NSEG;
    float* I1  = F2 + NSEG;
    float* I2  = I1 + NSEG;

    // Host-side coefficient + H = A^SEG computation (baked into graph args)
    IIRParams p;
    {
        const double w0    = 2.0 * PI_D * 1.0 / 16000.0;  // cutoff = 1 Hz
        const double alpha = sin(w0) / (2.0 * 0.707);
        const double cosw  = cos(w0);
        const double a0    = 1.0 + alpha;
        p.b0 = (float)((1.0 - cosw) / 2.0 / a0);
        p.b1 = (float)((1.0 - cosw) / a0);
        p.b2 = p.b0;
        p.a1 = (float)(-2.0 * cosw / a0);
        p.a2 = (float)((1.0 - alpha) / a0);

        double m00 = -(double)p.a1, m01 = -(double)p.a2, m10 = 1.0, m11 = 0.0;
        double h00 = 1, h01 = 0, h10 = 0, h11 = 1;
        int e = SEG;
        while (e > 0) {
            if (e & 1) {
                double t00 = h00*m00 + h01*m10, t01 = h00*m01 + h01*m11;
                double t10 = h10*m00 + h11*m10, t11 = h10*m01 + h11*m11;
                h00 = t00; h01 = t01; h10 = t10; h11 = t11;
            }
            e >>= 1;
            if (e) {
                double t00 = m00*m00 + m01*m10, t01 = m00*m01 + m01*m11;
                double t10 = m10*m00 + m11*m10, t11 = m10*m01 + m11*m11;
                m00 = t00; m01 = t01; m10 = t10; m11 = t11;
            }
        }
        p.h00 = h00; p.h01 = h01; p.h10 = h10; p.h11 = h11;
    }

    iir_phase1<<<SCAN_BLOCKS, SEGS_PER_BLOCK, 0, stream>>>(noise, F1, F2, p);
    iir_phase2<<<1, K2_THREADS, 0, stream>>>(F1, F2, I1, I2, p);
    iir_phase3<<<SCAN_BLOCKS, SEGS_PER_BLOCK, 0, stream>>>(noise, I1, I2, mod, p);

    mul_kernel<<<MUL_BLOCKS, MUL_THREADS, 0, stream>>>(
        (const fvec4*)x, mod, (fvec4*)out);
}